// Round 7
// baseline (145.571 us; speedup 1.0000x reference)
//
#include <hip/hip_runtime.h>

#define BATCH 64
#define NSAMP 1500
#define NFREQ 1251
#define FBLK  256             // freqs per block
#define FCHUNKS 5             // 5*256 = 1280 >= 1251
#define NQ    4               // sub-chains per signal (in-block)
#define QSTEP 376             // quarter starts: 0,376,752,1128 (4-aligned)

// ---------------------------------------------------------------------------
// Round 14: single dispatch; fix r6's two measured sins.
//  r6 post-mortem: fused kernel ~25-30 us because (1) 5 waves/CU (r1's known
//  latency-bound geometry) and (2) 64 serialized fetch_add(p,0) round-trips
//  in the global finisher. Fixes:
//   (1) 1024-thread blocks: thread (q = tid>>8, f = tid&255) runs a Goertzel
//       sub-chain over samples [376q, 376q+len), len = 376/376/376/372 (all
//       starts 4-aligned), rotates by start phase, LDS-combines across q in
//       fixed order. 320 blocks x 16 waves = 20 waves/CU -> dep-chain hidden.
//   (2) cross-block handoff uses r5's PROVEN protocol: plain stores +
//       __threadfence + arrival atomicAdd; consumer fence + PLAIN loads
//       (pipelined) - no RMW-read chains. Dirty data is ~KB, so fences are
//       cheap (r5's 132 us was the 3.2 MB of dirty bulk, not the fence).
// Arrival counters are poison-relative (probe words at +512 B; validated in
// r5/r6). psd regrouping across sub-chains is safe: r0/r1/r6 each used a
// different grouping, all measured absmax 0.0 (softmax prob at idx
// underflows to exact 0.0f -> per-sample loss = -log(1e-8) bitwise).
// ---------------------------------------------------------------------------

#define CTRL_CNT    0      // ctrl[0..63]   per-batch arrival counters
#define CTRL_GCNT   64     // ctrl[64]      global finisher counter
#define CTRL_PROBE  128    // ctrl[128+i]   poison probe for ctrl[i] (+512 B)
#define CTRL_PIDX   256    // ctrl[256+b]   psd[idx] bits per batch
#define CTRL_LVAL   320    // ctrl[320+b]   per-batch loss bits
#define CTRL_STATS  384    // float2 stats[b*FCHUNKS+c] from word 384 (640 words)

__global__ __launch_bounds__(1024) void fused_kernel(
    const float* __restrict__ x,          // [B,N]
    const float* __restrict__ f_true,     // [B]
    const float* __restrict__ fs,         // [B]
    const float* __restrict__ sampling_f, // [1]
    const float* __restrict__ f_range,    // f_min first
    unsigned* __restrict__ ctrl,          // control region (ws)
    float* __restrict__ out)              // [1]
{
    __shared__ float4 xs4[NSAMP / 4];     // 375 float4 = 6 KB (whole signal)
    __shared__ float2 comb[FBLK * NQ];    // 8 KB: per-(f,q) rotated partials
    __shared__ float red[16], red2[16];

    const int b      = blockIdx.x;
    const int fchunk = blockIdx.y;
    const int tid    = threadIdx.x;
    const int q      = tid >> 8;          // 0..3 (wave-uniform)
    const int f      = tid & 255;
    const int wave   = tid >> 6;
    const int lane   = tid & 63;

    // ---- stage whole signal ----
    const float4* xg = reinterpret_cast<const float4*>(x + b * NSAMP);
    if (tid < NSAMP / 4) xs4[tid] = xg[tid];
    __syncthreads();

    const float f_min = f_range[0];
    const float step  = sampling_f[0];
    const float delta = (f_min + step) - f_min;

    const int  fidx  = fchunk * FBLK + f;
    const bool valid = (fidx < NFREQ);

    // ---- per-(q,f) Goertzel sub-chain ----
    {
        const float fv  = f_min + (float)fidx * delta;
        const float rho = fv / fs[b];     // revolutions per sample
        float rf = rho - floorf(rho);
        const float coef = 2.0f * __builtin_amdgcn_cosf(rf);

        const int n0   = q * QSTEP;                  // 0,376,752,1128
        const int len  = (q < 3) ? QSTEP : (NSAMP - 3 * QSTEP);   // 376/372
        const int b4   = n0 >> 2;                    // float4 base
        const int len4 = len >> 2;                   // 94 or 93 (wave-uniform)

        float s1 = 0.0f, s2 = 0.0f;
#pragma unroll 4
        for (int k = 0; k < len4; ++k) {
            float4 v = xs4[b4 + k];
            float t;
            t = fmaf(coef, s1, v.x - s2); s2 = s1; s1 = t;
            t = fmaf(coef, s1, v.y - s2); s2 = s1; s1 = t;
            t = fmaf(coef, s1, v.z - s2); s2 = s1; s1 = t;
            t = fmaf(coef, s1, v.w - s2); s2 = s1; s1 = t;
        }

        float aM  = (float)len * rho;        aM  -= floorf(aM);
        float aM1 = (float)(len - 1) * rho;  aM1 -= floorf(aM1);
        float a0  = (float)n0 * rho;         a0  -= floorf(a0);
        const float cM  = __builtin_amdgcn_cosf(aM);
        const float sM  = __builtin_amdgcn_sinf(aM);
        const float cM1 = __builtin_amdgcn_cosf(aM1);
        const float sM1 = __builtin_amdgcn_sinf(aM1);
        const float c0  = __builtin_amdgcn_cosf(a0);
        const float s0  = __builtin_amdgcn_sinf(a0);

        const float Cl = cM1 * s1 - cM * s2;
        const float Sl = sM1 * s1 - sM * s2;
        comb[f * NQ + q] = make_float2(c0 * Cl - s0 * Sl,   // rotated C
                                       s0 * Cl + c0 * Sl);  // rotated S
    }
    __syncthreads();

    // ---- combine quarters (fixed q order), psd value in registers ----
    float v = 0.0f;
    if (q == 0 && valid) {
        float C = 0.0f, S = 0.0f;
#pragma unroll
        for (int qq = 0; qq < NQ; ++qq) {
            float2 p = comb[f * NQ + qq];
            C += p.x; S += p.y;
        }
        v = fmaf(C, C, S * S);
    }

    // ---- psd[idx] publish (plain store; covered by release fence below) ----
    if (q == 0 && valid) {
        const float ft = f_true[b];
        int iq2 = (int)((ft - f_min) / delta + 0.5f);
        int lo = iq2 - 2; if (lo < 0) lo = 0;
        int hi = iq2 + 2; if (hi > NFREQ - 1) hi = NFREQ - 1;
        int   idx   = lo;
        float bestd = fabsf((f_min + (float)lo * delta) - ft);
        for (int i = lo + 1; i <= hi; ++i) {
            float d = fabsf((f_min + (float)i * delta) - ft);
            if (d < bestd) { bestd = d; idx = i; }   // strict < : first occurrence
        }
        if (fidx == idx) ctrl[CTRL_PIDX + b] = __float_as_uint(v);
    }

    // ---- block-local online softmax over this chunk's 256 freqs ----
    const bool act = (q == 0) && valid;
    float mt = act ? v : -INFINITY;
    for (int off = 32; off > 0; off >>= 1) mt = fmaxf(mt, __shfl_xor(mt, off));
    if (lane == 0) red[wave] = mt;
    __syncthreads();
    float mb = red[0];
#pragma unroll
    for (int w = 1; w < 16; ++w) mb = fmaxf(mb, red[w]);
    float e = act ? __expf(v - mb) : 0.0f;
    for (int off = 32; off > 0; off >>= 1) e += __shfl_xor(e, off);
    if (lane == 0) red2[wave] = e;
    __syncthreads();
    float lb = red2[0];
#pragma unroll
    for (int w = 1; w < 16; ++w) lb += red2[w];

    // ---- publish stats, release, count arrival (r5's proven protocol) ----
    float2* stats = (float2*)(ctrl + CTRL_STATS);
    if (tid == 0) stats[b * FCHUNKS + fchunk] = make_float2(mb, lb);
    __threadfence();
    __syncthreads();
    if (tid != 0) return;

    const unsigned E   = ctrl[CTRL_PROBE + b];               // poison baseline
    const unsigned old = atomicAdd(&ctrl[CTRL_CNT + b], 1u);
    if (old - E != FCHUNKS - 1) return;

    // ---- batch finisher: acquire, plain loads, fixed chunk order ----
    __threadfence();
    float gm = -INFINITY, gl = 0.0f;
#pragma unroll
    for (int c = 0; c < FCHUNKS; ++c) {
        float2 p = stats[b * FCHUNKS + c];
        const float mn = fmaxf(gm, p.x);
        gl = gl * __expf(gm - mn) + p.y * __expf(p.x - mn);
        gm = mn;
    }
    const float pv  = __uint_as_float(ctrl[CTRL_PIDX + b]);
    const float sm  = __expf(pv - gm) / gl;
    const float per = -logf(sm + 1e-8f);

    ctrl[CTRL_LVAL + b] = __float_as_uint(per);
    __threadfence();
    const unsigned E2   = ctrl[CTRL_PROBE + CTRL_GCNT];      // poison baseline
    const unsigned old2 = atomicAdd(&ctrl[CTRL_GCNT], 1u);
    if (old2 - E2 != BATCH - 1) return;

    // ---- global finisher: acquire, 64 PLAIN loads (pipelined), b-ascending ----
    __threadfence();
    float total = 0.0f;
#pragma unroll 16
    for (int bb = 0; bb < BATCH; ++bb)
        total += __uint_as_float(ctrl[CTRL_LVAL + bb]);
    out[0] = total * (1.0f / (float)BATCH);   // exact 2^-6 scale
}

extern "C" void kernel_launch(void* const* d_in, const int* in_sizes, int n_in,
                              void* d_out, int out_size, void* d_ws, size_t ws_size,
                              hipStream_t stream) {
    const float* x          = (const float*)d_in[0];
    const float* f_true     = (const float*)d_in[1];
    const float* fs         = (const float*)d_in[2];
    // d_in[3] = deltas (unused)
    const float* sampling_f = (const float*)d_in[4];
    const float* f_range    = (const float*)d_in[5];

    unsigned* ctrl = (unsigned*)((char*)d_ws + (4u << 20)); // 4 MiB offset

    dim3 grid(BATCH, FCHUNKS);            // 320 blocks x 16 waves = 20 waves/CU
    fused_kernel<<<grid, 1024, 0, stream>>>(x, f_true, fs, sampling_f, f_range,
                                            ctrl, (float*)d_out);
}

// Round 8
// 81.009 us; speedup vs baseline: 1.7970x; 1.7970x over previous
//
#include <hip/hip_runtime.h>

#define BATCH 64
#define NSAMP 1500
#define NFREQ 1251
#define NSEG  5
#define SEGLEN 300            // NSEG*SEGLEN == NSAMP
#define FBLK  256             // freqs per block
#define FCHUNKS 5             // 5*256 = 1280 >= 1251

// ---------------------------------------------------------------------------
// Round 15: r6 (fence-free single dispatch, atomic-RMW-only handoff, proven
// absmax 0.0) with the measured serial tails parallelized.
// Ledger: grid.sync 271 us (r3); per-wave device fences 87-132 us regardless
// of dirty bytes (r5/r7 - cost is per fence execution, NOT per byte); r6
// fence-free kernel ~25-30 us = Goertzel ~4 + a 64-iteration ROLLED
// coherence-point RMW read loop in one thread (~0.4 us/iter) ~24.
// Fix: keep the whole block alive at finisher stages; lanes issue the RMW
// reads IN PARALLEL (6 for batch stats+pidx, 64 for the final mean), stage
// into LDS, thread 0 combines in the exact proven fixed order.
// Everything else is bit-identical r6: counters poison-relative (probe at
// +512 B), relaxed exch publish -> acq_rel arrival add (validated pairing),
// psd regrouping safe (r0/r1/r6: softmax prob at idx underflows to exact
// 0.0f -> per-sample loss = -log(1e-8) bitwise).
// ---------------------------------------------------------------------------

#define CTRL_CNT    0      // ctrl[0..63]   per-batch arrival counters
#define CTRL_GCNT   64     // ctrl[64]      global finisher counter
#define CTRL_PROBE  128    // ctrl[128+i]   poison probe for ctrl[i] (+512 B)
#define CTRL_PIDX   256    // ctrl[256+b]   psd[idx] bits per batch
#define CTRL_LVAL   320    // ctrl[320+b]   per-batch loss bits
#define CTRL_STATS  384    // ull stats[b*FCHUNKS+c] at words 384+2*(...)

__device__ __forceinline__ unsigned rmw_read32(unsigned* p) {
    return __hip_atomic_fetch_add(p, 0u, __ATOMIC_RELAXED, __HIP_MEMORY_SCOPE_AGENT);
}
__device__ __forceinline__ unsigned long long rmw_read64(unsigned long long* p) {
    return __hip_atomic_fetch_add(p, 0ull, __ATOMIC_RELAXED, __HIP_MEMORY_SCOPE_AGENT);
}

__global__ __launch_bounds__(256) void fused_kernel(
    const float* __restrict__ x,          // [B,N]
    const float* __restrict__ f_true,     // [B]
    const float* __restrict__ fs,         // [B]
    const float* __restrict__ sampling_f, // [1]
    const float* __restrict__ f_range,    // f_min first
    unsigned* __restrict__ ctrl,          // control region (ws)
    float* __restrict__ out)              // [1]
{
    __shared__ float4 xs4[NSAMP / 4];     // 375 float4 = 6 KB (whole signal)
    __shared__ float red[4], red2[4];
    __shared__ unsigned s_arr, s_gflag;
    __shared__ float2 s_stats[FCHUNKS];
    __shared__ float s_pidx;
    __shared__ float s_lvals[BATCH];

    const int b      = blockIdx.x;
    const int fchunk = blockIdx.y;
    const int tid    = threadIdx.x;
    const int wave   = tid >> 6;
    const int lane   = tid & 63;

    unsigned long long* stats = (unsigned long long*)(ctrl + CTRL_STATS);

    // ---- phase 1: r1/r6's proven fused-segment Goertzel (bit-identical) ----
    const float4* xg = reinterpret_cast<const float4*>(x + b * NSAMP);
    for (int i = tid; i < NSAMP / 4; i += FBLK) xs4[i] = xg[i];
    __syncthreads();

    const float f_min = f_range[0];
    const float step  = sampling_f[0];
    const float delta = (f_min + step) - f_min;

    const int  fidx  = fchunk * FBLK + tid;
    const bool valid = (fidx < NFREQ);

    float v = 0.0f;                       // psd value (registers only)
    if (valid) {
        const float fv  = f_min + (float)fidx * delta;
        const float rho = fv / fs[b];     // revolutions per sample
        float rf = rho - floorf(rho);
        const float coef = 2.0f * __builtin_amdgcn_cosf(rf);

        float s1[NSEG], s2[NSEG];
#pragma unroll
        for (int g = 0; g < NSEG; ++g) { s1[g] = 0.0f; s2[g] = 0.0f; }

#pragma unroll 3
        for (int k = 0; k < SEGLEN / 4; ++k) {
#pragma unroll
            for (int g = 0; g < NSEG; ++g) {
                float4 vv = xs4[g * (SEGLEN / 4) + k];
                float t;
                t = fmaf(coef, s1[g], vv.x - s2[g]); s2[g] = s1[g]; s1[g] = t;
                t = fmaf(coef, s1[g], vv.y - s2[g]); s2[g] = s1[g]; s1[g] = t;
                t = fmaf(coef, s1[g], vv.z - s2[g]); s2[g] = s1[g]; s1[g] = t;
                t = fmaf(coef, s1[g], vv.w - s2[g]); s2[g] = s1[g]; s1[g] = t;
            }
        }

        float aM  = (float)SEGLEN * rho;        aM  -= floorf(aM);
        float aM1 = (float)(SEGLEN - 1) * rho;  aM1 -= floorf(aM1);
        const float cM  = __builtin_amdgcn_cosf(aM);
        const float sM  = __builtin_amdgcn_sinf(aM);
        const float cM1 = __builtin_amdgcn_cosf(aM1);
        const float sM1 = __builtin_amdgcn_sinf(aM1);

        float C = 0.0f, S = 0.0f;
#pragma unroll
        for (int g = 0; g < NSEG; ++g) {
            float a0 = (float)(g * SEGLEN) * rho;  a0 -= floorf(a0);
            const float c0 = __builtin_amdgcn_cosf(a0);
            const float s0 = __builtin_amdgcn_sinf(a0);
            const float Cl = cM1 * s1[g] - cM * s2[g];
            const float Sl = sM1 * s1[g] - sM * s2[g];
            C += c0 * Cl - s0 * Sl;
            S += s0 * Cl + c0 * Sl;
        }
        v = fmaf(C, C, S * S);
    }

    // ---- closed-form argmin + psd[idx] publish (coherence-point RMW) ----
    const float ft = f_true[b];
    int iq = (int)((ft - f_min) / delta + 0.5f);
    int lo = iq - 2; if (lo < 0) lo = 0;
    int hi = iq + 2; if (hi > NFREQ - 1) hi = NFREQ - 1;
    int   idx   = lo;
    float bestd = fabsf((f_min + (float)lo * delta) - ft);
    for (int i = lo + 1; i <= hi; ++i) {
        float d = fabsf((f_min + (float)i * delta) - ft);
        if (d < bestd) { bestd = d; idx = i; }     // strict < : first occurrence
    }
    if (valid && fidx == idx)
        __hip_atomic_exchange(&ctrl[CTRL_PIDX + b], __float_as_uint(v),
                              __ATOMIC_RELAXED, __HIP_MEMORY_SCOPE_AGENT);

    // ---- block-local online softmax: m_blk, l_blk ----
    float mt = valid ? v : -INFINITY;
    for (int off = 32; off > 0; off >>= 1) mt = fmaxf(mt, __shfl_xor(mt, off));
    if (lane == 0) red[wave] = mt;
    __syncthreads();
    const float mb = fmaxf(fmaxf(red[0], red[1]), fmaxf(red[2], red[3]));
    float e = valid ? __expf(v - mb) : 0.0f;
    for (int off = 32; off > 0; off >>= 1) e += __shfl_xor(e, off);
    if (lane == 0) red2[wave] = e;
    __syncthreads();                      // drains idx-owner's exch too
    const float lb = red2[0] + red2[1] + red2[2] + red2[3];

    // ---- publish block stats, count arrival (r6's proven protocol) ----
    if (tid == 0) {
        unsigned long long p =
            ((unsigned long long)__float_as_uint(lb) << 32) | __float_as_uint(mb);
        __hip_atomic_exchange(&stats[b * FCHUNKS + fchunk], p,
                              __ATOMIC_RELAXED, __HIP_MEMORY_SCOPE_AGENT);
        const unsigned E = rmw_read32(&ctrl[CTRL_PROBE + b]);
        const unsigned old = __hip_atomic_fetch_add(&ctrl[CTRL_CNT + b], 1u,
                              __ATOMIC_ACQ_REL, __HIP_MEMORY_SCOPE_AGENT);
        s_arr = old - E;                  // 0..4, wraparound-safe
    }
    __syncthreads();
    if (s_arr != FCHUNKS - 1) return;     // whole non-last block exits

    // ---- batch finisher: PARALLEL coherence-point reads, staged to LDS ----
    if (tid < FCHUNKS) {
        unsigned long long p = rmw_read64(&stats[b * FCHUNKS + tid]);
        s_stats[tid] = make_float2(__uint_as_float((unsigned)p),          // m
                                   __uint_as_float((unsigned)(p >> 32))); // l
    }
    if (tid == 8) s_pidx = __uint_as_float(rmw_read32(&ctrl[CTRL_PIDX + b]));
    __syncthreads();

    if (tid == 0) {
        float gm = -INFINITY, gl = 0.0f;
#pragma unroll
        for (int c = 0; c < FCHUNKS; ++c) {       // fixed chunk order
            const float mc = s_stats[c].x, lc = s_stats[c].y;
            const float mn = fmaxf(gm, mc);
            gl = gl * __expf(gm - mn) + lc * __expf(mc - mn);
            gm = mn;
        }
        const float sm  = __expf(s_pidx - gm) / gl;
        const float per = -logf(sm + 1e-8f);

        __hip_atomic_exchange(&ctrl[CTRL_LVAL + b], __float_as_uint(per),
                              __ATOMIC_RELAXED, __HIP_MEMORY_SCOPE_AGENT);
        const unsigned E2   = rmw_read32(&ctrl[CTRL_PROBE + CTRL_GCNT]);
        const unsigned old2 = __hip_atomic_fetch_add(&ctrl[CTRL_GCNT], 1u,
                              __ATOMIC_ACQ_REL, __HIP_MEMORY_SCOPE_AGENT);
        s_gflag = (old2 - E2 == BATCH - 1) ? 1u : 0u;
    }
    __syncthreads();
    if (s_gflag != 1u) return;

    // ---- global finisher: 64 PARALLEL reads, fixed b-ascending sum ----
    if (tid < BATCH)
        s_lvals[tid] = __uint_as_float(rmw_read32(&ctrl[CTRL_LVAL + tid]));
    __syncthreads();
    if (tid == 0) {
        float total = 0.0f;
#pragma unroll 16
        for (int bb = 0; bb < BATCH; ++bb)        // proven sequential order
            total += s_lvals[bb];
        out[0] = total * (1.0f / (float)BATCH);   // exact 2^-6 scale
    }
}

extern "C" void kernel_launch(void* const* d_in, const int* in_sizes, int n_in,
                              void* d_out, int out_size, void* d_ws, size_t ws_size,
                              hipStream_t stream) {
    const float* x          = (const float*)d_in[0];
    const float* f_true     = (const float*)d_in[1];
    const float* fs         = (const float*)d_in[2];
    // d_in[3] = deltas (unused)
    const float* sampling_f = (const float*)d_in[4];
    const float* f_range    = (const float*)d_in[5];

    unsigned* ctrl = (unsigned*)((char*)d_ws + (4u << 20)); // 4 MiB offset

    dim3 grid(BATCH, FCHUNKS);            // 320 blocks x 4 waves
    fused_kernel<<<grid, FBLK, 0, stream>>>(x, f_true, fs, sampling_f, f_range,
                                            ctrl, (float*)d_out);
}